// Round 2
// baseline (3023.736 us; speedup 1.0000x reference)
//
#include <hip/hip_runtime.h>
#include <cstddef>
#include <cstdint>

// LSTM_27934467293427 — R6: single-wave recurrence, zero barriers.
// R5 post-mortem: per-step cost (~1780 cy) is cross-wave sync structure
// (barrier + LDS h round trip + shuffle reduce), not vmcnt drain. Fix: one
// wave per block. Lane p owns h[p], c[p], and all 4 gate weight rows in
// VGPRs (256 regs). h broadcast via 16 same-address ds_read_b128 (free
// broadcast). Single wave => DS pipe in-order => NO barriers at all. Gate
// dots are lane-local (no reduce). Head dots ride the same broadcast reads
// on lanes 0..25 (zero weights elsewhere), one-step lagged as before.
// FMAs packed as float2 -> v_pk_fma_f32 (VOP3P) to halve issue.
// K1 (gx = X·Wih^T + bias, split-bf16 MFMA) unchanged.

namespace {

constexpr int B_ = 256, S_ = 2048, E_ = 128, H_ = 64, G_ = 256, H2_ = 2;

typedef short short8 __attribute__((ext_vector_type(8)));
typedef float f4 __attribute__((ext_vector_type(4)));
typedef float f2 __attribute__((ext_vector_type(2)));

__device__ __forceinline__ float sigm(float x) {
    return __builtin_amdgcn_rcpf(1.0f + __expf(-x));
}
__device__ __forceinline__ float tanh_fast(float x) {
    return 1.0f - 2.0f * __builtin_amdgcn_rcpf(1.0f + __expf(2.0f * x));
}
__device__ __forceinline__ float dot4(float4 a, float4 b) {
    return a.x * b.x + a.y * b.y + a.z * b.z + a.w * b.w;
}
__device__ __forceinline__ short f2bf(float f) {  // RNE float->bf16
    union { float f; uint32_t u; } a; a.f = f;
    uint32_t r = a.u + 0x7FFFu + ((a.u >> 16) & 1u);
    return (short)(r >> 16);
}
__device__ __forceinline__ float bf2f(short s) {
    union { uint32_t u; float f; } a; a.u = ((uint32_t)(uint16_t)s) << 16;
    return a.f;
}
__device__ __forceinline__ void cvt8(float4 a, float4 b, short8& hi, short8& lo) {
    float v[8] = {a.x, a.y, a.z, a.w, b.x, b.y, b.z, b.w};
    #pragma unroll
    for (int i = 0; i < 8; ++i) {
        short h = f2bf(v[i]);
        hi[i] = h;
        lo[i] = f2bf(v[i] - bf2f(h));
    }
}

// ---------------- K1: gx[b][tau][j] = sum_e x[b,cs+tau,e]*Wih[j,e] + bias[j] ----
// grid (B*Tc/128, 2), 256 thr. Wave w owns 32 cols; block owns 128 rows (8 slabs).
// MFMA 16x16x32 bf16, split precision: Ah*Bh + Al*Bh + Ah*Bl.
__global__ __launch_bounds__(256) void k1_gemm(
    const float* __restrict__ x, const int* __restrict__ lengths,
    const float* __restrict__ Wih, const float* __restrict__ bih,
    const float* __restrict__ bhh, float* __restrict__ gx, int cs, int tcLog)
{
    const int Tc = 1 << tcLog;
    const int t = threadIdx.x;
    const int lane = t & 63, wv = t >> 6;
    const int lm = lane & 15, quad = lane >> 4;
    const int nbase = blockIdx.y * 128 + wv * 32;
    const int rowblk = blockIdx.x * 128;

    // B-fragments (weights), held in registers for all 8 slabs.
    short8 Bh[2][4], Bl[2][4];
    float bias[2];
    #pragma unroll
    for (int nt = 0; nt < 2; ++nt) {
        const int n = nbase + nt * 16 + lm;
        bias[nt] = bih[n] + bhh[n];
        #pragma unroll
        for (int kk = 0; kk < 4; ++kk) {
            const float4* wp = (const float4*)(Wih + n * E_ + kk * 32 + quad * 8);
            cvt8(wp[0], wp[1], Bh[nt][kk], Bl[nt][kk]);
        }
    }

    for (int slab = 0; slab < 8; ++slab) {
        const int row0 = rowblk + slab * 16;
        const int b = row0 >> tcLog;
        const int tb = row0 & (Tc - 1);
        int len = lengths[b]; len = len < 1 ? 1 : (len > S_ ? S_ : len);
        if (cs + tb >= len) continue;

        // A-fragments: row m = lm, k = quad*8 + j (+32*kk)
        const float* xr = x + ((size_t)b * S_ + cs + tb + lm) * E_;
        short8 Ah[4], Al[4];
        #pragma unroll
        for (int kk = 0; kk < 4; ++kk) {
            const float4* ap = (const float4*)(xr + kk * 32 + quad * 8);
            cvt8(ap[0], ap[1], Ah[kk], Al[kk]);
        }
        f4 acc[2] = {{0,0,0,0},{0,0,0,0}};
        #pragma unroll
        for (int kk = 0; kk < 4; ++kk) {
            #pragma unroll
            for (int nt = 0; nt < 2; ++nt) {
                acc[nt] = __builtin_amdgcn_mfma_f32_16x16x32_bf16(Ah[kk], Bh[nt][kk], acc[nt], 0, 0, 0);
                acc[nt] = __builtin_amdgcn_mfma_f32_16x16x32_bf16(Al[kk], Bh[nt][kk], acc[nt], 0, 0, 0);
                acc[nt] = __builtin_amdgcn_mfma_f32_16x16x32_bf16(Ah[kk], Bl[nt][kk], acc[nt], 0, 0, 0);
            }
        }
        // D: col = lane&15, row = quad*4 + r (m89/m91-verified)
        float* gp = gx + ((size_t)b * Tc + tb) * G_;
        #pragma unroll
        for (int nt = 0; nt < 2; ++nt) {
            #pragma unroll
            for (int r = 0; r < 4; ++r) {
                gp[(quad * 4 + r) * G_ + nbase + nt * 16 + lm] = acc[nt][r] + bias[nt];
            }
        }
    }
}

// ---------------- K2: single-wave recurrence over one chunk [cs, cs+Tc) --------
// grid(B), block(64). Lane p owns h[p], c[p], gate rows {i,f,g,o}*64+p of Whh.
// Lanes 0..25 additionally own head row r=p (r = k*2+o) of hWih.
__global__ __launch_bounds__(64, 1) void k2_recur(
    const float* __restrict__ gx, const int* __restrict__ lengths,
    const float* __restrict__ Whh, const float* __restrict__ hWih,
    const float* __restrict__ hWhh, const float* __restrict__ hbih,
    const float* __restrict__ hbhh, float* __restrict__ out,
    float* __restrict__ stH, float* __restrict__ stC, float* __restrict__ stHK,
    int cs, int Tc)
{
    const int b = blockIdx.x, p = threadIdx.x;
    int len = lengths[b]; len = len < 1 ? 1 : (len > S_ ? S_ : len);
    if (cs > len) return;
    const int ce = cs + Tc;

    __shared__ __align__(16) float hbuf[2][H_];

    // Gate weights: lane p holds rows g*64+p (g = 0:i, 1:f, 2:g, 3:o), as f2.
    f2 w2[4][32];
    #pragma unroll
    for (int g = 0; g < 4; ++g) {
        const f2* wp = (const f2*)(Whh + (size_t)(g * 64 + p) * H_);
        #pragma unroll
        for (int ch = 0; ch < 32; ++ch) w2[g][ch] = wp[ch];
    }

    // Head weights: lane r = p < 26 holds hWih row r (r = k*2+o).
    const bool isHead = p < 26;
    f2 wk2[32];
    float hb = 0.f, w0 = 0.f, w1 = 0.f;
    if (isHead) {
        const f2* kp = (const f2*)(hWih + (size_t)p * H_);
        #pragma unroll
        for (int ch = 0; ch < 32; ++ch) wk2[ch] = kp[ch];
        hb = hbih[p] + hbhh[p];
        w0 = hWhh[p * 2 + 0];
        w1 = hWhh[p * 2 + 1];
    } else {
        #pragma unroll
        for (int ch = 0; ch < 32; ++ch) wk2[ch] = (f2){0.f, 0.f};
    }

    float c = 0.f, h = 0.f, hk = 0.f;
    if (cs == 0) {
        hbuf[0][p] = 0.f;
    } else {
        h = stH[b * 64 + p];
        c = stC[b * 64 + p];
        if (isHead) hk = stHK[b * 26 + p];
        hbuf[cs & 1][p] = h;
    }
    // single wave: DS pipe is in-order, no barrier needed anywhere.

    // gx prefetch (distance 2): lane p reads gates at columns g*64+p.
    const float* gxp = gx + (size_t)b * Tc * G_ + p;
    float ga0 = 0.f, ga1 = 0.f, ga2 = 0.f, ga3 = 0.f;
    float gb0 = 0.f, gb1 = 0.f, gb2 = 0.f, gb3 = 0.f;
    if (cs < len) {
        ga0 = gxp[0]; ga1 = gxp[64]; ga2 = gxp[128]; ga3 = gxp[192];
    }
    if (cs + 1 < len && cs + 1 < ce) {
        const float* r = gxp + G_;
        gb0 = r[0]; gb1 = r[64]; gb2 = r[128]; gb3 = r[192];
    }

    for (int u = cs; u < ce; ++u) {
        const float* hrow = hbuf[u & 1];   // h_{u-1}, broadcast reads
        f2 a0 = {0.f, 0.f}, a1 = {0.f, 0.f}, a2 = {0.f, 0.f}, a3 = {0.f, 0.f};
        f2 ak = {0.f, 0.f};
        #pragma unroll
        for (int q4 = 0; q4 < 16; ++q4) {
            const float4 hv = *(const float4*)(hrow + q4 * 4);
            const f2 hA = {hv.x, hv.y};
            const f2 hB = {hv.z, hv.w};
            a0 = __builtin_elementwise_fma(w2[0][q4 * 2],     hA, a0);
            a1 = __builtin_elementwise_fma(w2[1][q4 * 2],     hA, a1);
            a2 = __builtin_elementwise_fma(w2[2][q4 * 2],     hA, a2);
            a3 = __builtin_elementwise_fma(w2[3][q4 * 2],     hA, a3);
            ak = __builtin_elementwise_fma(wk2[q4 * 2],       hA, ak);
            a0 = __builtin_elementwise_fma(w2[0][q4 * 2 + 1], hB, a0);
            a1 = __builtin_elementwise_fma(w2[1][q4 * 2 + 1], hB, a1);
            a2 = __builtin_elementwise_fma(w2[2][q4 * 2 + 1], hB, a2);
            a3 = __builtin_elementwise_fma(w2[3][q4 * 2 + 1], hB, a3);
            ak = __builtin_elementwise_fma(wk2[q4 * 2 + 1],   hB, ak);
        }

        // head: hk_{u-1} = tanh(hWih·h_{u-1} + hb + hWhh·hk_{u-2})
        if (u >= 1) {
            const float ah = ak[0] + ak[1] + hb;
            const float partner = __shfl_xor(hk, 1);
            const float h0 = (p & 1) ? partner : hk;
            const float h1 = (p & 1) ? hk : partner;
            const float hkn = tanh_fast(ah + w0 * h0 + w1 * h1);
            if (isHead) hk = hkn;
            if (u == len) {   // uniform across the wave
                if (isHead) out[((p >> 1) * B_ + b) * H2_ + (p & 1)] = sigm(hk);
                return;
            }
        }

        // gates (lane-local, no reduce)
        const float vi = a0[0] + a0[1] + ga0;
        const float vf = a1[0] + a1[1] + ga1;
        const float vg = a2[0] + a2[1] + ga2;
        const float vo = a3[0] + a3[1] + ga3;
        c = sigm(vf) * c + sigm(vi) * tanh_fast(vg);
        h = sigm(vo) * tanh_fast(c);
        hbuf[(u + 1) & 1][p] = h;

        // rotate prefetch
        ga0 = gb0; ga1 = gb1; ga2 = gb2; ga3 = gb3;
        const int un = u + 2;
        if (un < len && un < ce) {
            const float* r = gxp + (size_t)(un - cs) * G_;
            gb0 = r[0]; gb1 = r[64]; gb2 = r[128]; gb3 = r[192];
        } else {
            gb0 = gb1 = gb2 = gb3 = 0.f;
        }
    }

    // chunk fully processed (len >= ce): persist state
    stH[b * 64 + p] = h;
    stC[b * 64 + p] = c;
    if (isHead) stHK[b * 26 + p] = hk;

    if (ce == S_ && len == S_) {
        // lagged final head for h_{S-1} (in hbuf[S_&1], written at u=S_-1)
        const float* hrow = hbuf[S_ & 1];
        f2 ak = {0.f, 0.f};
        #pragma unroll
        for (int ch = 0; ch < 32; ++ch) {
            const f2 hA = *(const f2*)(hrow + ch * 2);
            ak = __builtin_elementwise_fma(wk2[ch], hA, ak);
        }
        const float ah = ak[0] + ak[1] + hb;
        const float partner = __shfl_xor(hk, 1);
        const float h0 = (p & 1) ? partner : hk;
        const float h1 = (p & 1) ? hk : partner;
        const float hkn = tanh_fast(ah + w0 * h0 + w1 * h1);
        if (isHead) out[((p >> 1) * B_ + b) * H2_ + (p & 1)] = sigm(hkn);
    }
}

}  // namespace

extern "C" void kernel_launch(void* const* d_in, const int* in_sizes, int n_in,
                              void* d_out, int out_size, void* d_ws, size_t ws_size,
                              hipStream_t stream) {
    const float* x    = (const float*)d_in[0];
    const int*   len  = (const int*)d_in[1];
    const float* Wih  = (const float*)d_in[2];
    const float* Whh  = (const float*)d_in[3];
    const float* bih  = (const float*)d_in[4];
    const float* bhh  = (const float*)d_in[5];
    const float* hWih = (const float*)d_in[6];
    const float* hWhh = (const float*)d_in[7];
    const float* hbih = (const float*)d_in[8];
    const float* hbhh = (const float*)d_in[9];
    float* out = (float*)d_out;

    // pick chunk length fitting the workspace (gx chunk + 160KB state)
    int tcLog = 8;  // Tc = 256
    while (tcLog > 5) {
        size_t need = (size_t)B_ * ((size_t)1 << tcLog) * G_ * 4 + 160 * 1024;
        if (need <= ws_size) break;
        --tcLog;
    }
    const int Tc = 1 << tcLog;
    float* gxbuf = (float*)d_ws;
    size_t gxBytes = (size_t)B_ * Tc * G_ * 4;
    float* stH  = (float*)((char*)d_ws + gxBytes);
    float* stC  = stH + B_ * 64;
    float* stHK = stC + B_ * 64;   // B*26 floats used

    for (int cs = 0; cs < S_; cs += Tc) {
        dim3 g1(B_ * Tc / 128, 2);
        hipLaunchKernelGGL(k1_gemm, g1, dim3(256), 0, stream,
                           x, len, Wih, bih, bhh, gxbuf, cs, tcLog);
        hipLaunchKernelGGL(k2_recur, dim3(B_), dim3(64), 0, stream,
                           gxbuf, len, Whh, hWih, hWhh, hbih, hbhh, out,
                           stH, stC, stHK, cs, Tc);
    }
}

// Round 3
// 1984.582 us; speedup vs baseline: 1.5236x; 1.5236x over previous
//
#include <hip/hip_runtime.h>
#include <cstddef>
#include <cstdint>

// LSTM_27934467293427 — R7: MFMA recurrence, 1 batch/block, zero shuffles.
// R6 post-mortem: w2[4][32] = 256 VGPRs of weights -> spill (VGPR_Count 216),
// scratch reloads every step = 2870cy/step. R4's 1780cy = DS-pipe contention
// (55 DS ops/step incl. 6-deep shuffle chains through one DS pipe) + 2 LDS
// round trips.
// R7: h·Whh^T via MFMA 16x16x32 split-bf16. Weights in B-fragments (64 VGPR
// total for 4 gates hi+lo). h in LDS as bf16 hi/lo rows (128B). With 1 batch,
// A-frag reads are quad-broadcast (same addr per 16-lane group) -> conflict-
// free, and A rows are replicated -> all D rows equal -> every lane holds its
// column's preacts: NO shuffles, lane-local activation. One lgkm-only barrier
// per step. Head = 12 MFMAs on wave 4 sharing the same broadcast A-frags.
// K1 (gx = X·Wih^T + bias, split-bf16 MFMA) unchanged.

namespace {

constexpr int B_ = 256, S_ = 2048, E_ = 128, H_ = 64, G_ = 256, H2_ = 2;

typedef short short8 __attribute__((ext_vector_type(8)));
typedef float f4 __attribute__((ext_vector_type(4)));

__device__ __forceinline__ float sigm(float x) {
    return __builtin_amdgcn_rcpf(1.0f + __expf(-x));
}
__device__ __forceinline__ float tanh_fast(float x) {
    return 1.0f - 2.0f * __builtin_amdgcn_rcpf(1.0f + __expf(2.0f * x));
}
__device__ __forceinline__ short f2bf(float f) {  // RNE float->bf16
    union { float f; uint32_t u; } a; a.f = f;
    uint32_t r = a.u + 0x7FFFu + ((a.u >> 16) & 1u);
    return (short)(r >> 16);
}
__device__ __forceinline__ float bf2f(short s) {
    union { uint32_t u; float f; } a; a.u = ((uint32_t)(uint16_t)s) << 16;
    return a.f;
}
__device__ __forceinline__ void cvt8(float4 a, float4 b, short8& hi, short8& lo) {
    float v[8] = {a.x, a.y, a.z, a.w, b.x, b.y, b.z, b.w};
    #pragma unroll
    for (int i = 0; i < 8; ++i) {
        short h = f2bf(v[i]);
        hi[i] = h;
        lo[i] = f2bf(v[i] - bf2f(h));
    }
}

// LDS-only barrier: does NOT drain vmcnt, so global prefetch stays in flight.
__device__ __forceinline__ void sync_lds_only() {
    asm volatile("s_waitcnt lgkmcnt(0)" ::: "memory");
    __builtin_amdgcn_s_barrier();
    asm volatile("" ::: "memory");
}

// ---------------- K1: gx[b][tau][j] = sum_e x[b,cs+tau,e]*Wih[j,e] + bias[j] ----
__global__ __launch_bounds__(256) void k1_gemm(
    const float* __restrict__ x, const int* __restrict__ lengths,
    const float* __restrict__ Wih, const float* __restrict__ bih,
    const float* __restrict__ bhh, float* __restrict__ gx, int cs, int tcLog)
{
    const int Tc = 1 << tcLog;
    const int t = threadIdx.x;
    const int lane = t & 63, wv = t >> 6;
    const int lm = lane & 15, quad = lane >> 4;
    const int nbase = blockIdx.y * 128 + wv * 32;
    const int rowblk = blockIdx.x * 128;

    short8 Bh[2][4], Bl[2][4];
    float bias[2];
    #pragma unroll
    for (int nt = 0; nt < 2; ++nt) {
        const int n = nbase + nt * 16 + lm;
        bias[nt] = bih[n] + bhh[n];
        #pragma unroll
        for (int kk = 0; kk < 4; ++kk) {
            const float4* wp = (const float4*)(Wih + n * E_ + kk * 32 + quad * 8);
            cvt8(wp[0], wp[1], Bh[nt][kk], Bl[nt][kk]);
        }
    }

    for (int slab = 0; slab < 8; ++slab) {
        const int row0 = rowblk + slab * 16;
        const int b = row0 >> tcLog;
        const int tb = row0 & (Tc - 1);
        int len = lengths[b]; len = len < 1 ? 1 : (len > S_ ? S_ : len);
        if (cs + tb >= len) continue;

        const float* xr = x + ((size_t)b * S_ + cs + tb + lm) * E_;
        short8 Ah[4], Al[4];
        #pragma unroll
        for (int kk = 0; kk < 4; ++kk) {
            const float4* ap = (const float4*)(xr + kk * 32 + quad * 8);
            cvt8(ap[0], ap[1], Ah[kk], Al[kk]);
        }
        f4 acc[2] = {{0,0,0,0},{0,0,0,0}};
        #pragma unroll
        for (int kk = 0; kk < 4; ++kk) {
            #pragma unroll
            for (int nt = 0; nt < 2; ++nt) {
                acc[nt] = __builtin_amdgcn_mfma_f32_16x16x32_bf16(Ah[kk], Bh[nt][kk], acc[nt], 0, 0, 0);
                acc[nt] = __builtin_amdgcn_mfma_f32_16x16x32_bf16(Al[kk], Bh[nt][kk], acc[nt], 0, 0, 0);
                acc[nt] = __builtin_amdgcn_mfma_f32_16x16x32_bf16(Ah[kk], Bl[nt][kk], acc[nt], 0, 0, 0);
            }
        }
        float* gp = gx + ((size_t)b * Tc + tb) * G_;
        #pragma unroll
        for (int nt = 0; nt < 2; ++nt) {
            #pragma unroll
            for (int r = 0; r < 4; ++r) {
                gp[(quad * 4 + r) * G_ + nbase + nt * 16 + lm] = acc[nt][r] + bias[nt];
            }
        }
    }
}

// ---------------- K2: MFMA recurrence, grid(B), block(320) -------------------
// waves 0..3: gates (wave w owns cols j = w*16+lm for all 4 gates), wave 4: head.
__global__ __launch_bounds__(320, 1) void k2_recur(
    const float* __restrict__ gx, const int* __restrict__ lengths,
    const float* __restrict__ Whh, const float* __restrict__ hWih,
    const float* __restrict__ hWhh, const float* __restrict__ hbih,
    const float* __restrict__ hbhh, float* __restrict__ out,
    float* __restrict__ stH, float* __restrict__ stC, float* __restrict__ stHK,
    int cs, int Tc)
{
    const int b = blockIdx.x, t = threadIdx.x;
    int len = lengths[b]; len = len < 1 ? 1 : (len > S_ ? S_ : len);
    if (cs > len) return;
    const int ce = cs + Tc;
    const int wave = t >> 6, lane = t & 63, lm = lane & 15, quad = lane >> 4;
    const bool isGate = wave < 4;
    const int w = wave;

    // h as bf16 hi/lo, double-buffered: [parity][hi=0/lo=1][k]
    __shared__ __align__(16) unsigned short hbuf[2][2][H_];

    // ---- loop-invariant weight fragments ----
    short8 Bh[4][2], Bl[4][2];     // gate waves: [gate][kchunk]
    short8 KBh[2][2], KBl[2][2];   // head wave: [tile][kchunk]
    float hbA = 0.f, w0A = 0.f, w1A = 0.f, hbB = 0.f, w0B = 0.f, w1B = 0.f;
    if (isGate) {
        #pragma unroll
        for (int g = 0; g < 4; ++g) {
            const int n = g * 64 + w * 16 + lm;
            #pragma unroll
            for (int kc = 0; kc < 2; ++kc) {
                const float4* wp = (const float4*)(Whh + (size_t)n * H_ + kc * 32 + quad * 8);
                cvt8(wp[0], wp[1], Bh[g][kc], Bl[g][kc]);
            }
        }
    } else {
        // tile 0: rows r = lm (0..15); tile 1: rows r = 16+lm (valid lm<10)
        #pragma unroll
        for (int kc = 0; kc < 2; ++kc) {
            const float4* kp = (const float4*)(hWih + (size_t)lm * H_ + kc * 32 + quad * 8);
            cvt8(kp[0], kp[1], KBh[0][kc], KBl[0][kc]);
        }
        if (lm < 10) {
            #pragma unroll
            for (int kc = 0; kc < 2; ++kc) {
                const float4* kp = (const float4*)(hWih + (size_t)(16 + lm) * H_ + kc * 32 + quad * 8);
                cvt8(kp[0], kp[1], KBh[1][kc], KBl[1][kc]);
            }
            hbB = hbih[16 + lm] + hbhh[16 + lm];
            w0B = hWhh[(16 + lm) * 2 + 0];
            w1B = hWhh[(16 + lm) * 2 + 1];
        } else {
            #pragma unroll
            for (int kc = 0; kc < 2; ++kc) {
                KBh[1][kc] = (short8)(short)0;
                KBl[1][kc] = (short8)(short)0;
            }
        }
        hbA = hbih[lm] + hbhh[lm];
        w0A = hWhh[lm * 2 + 0];
        w1A = hWhh[lm * 2 + 1];
    }

    // ---- state init / restore ----
    float c = 0.f, h = 0.f, hkA = 0.f, hkB = 0.f;
    if (cs == 0) {
        if (t < 128) ((unsigned short*)hbuf)[t] = 0;   // zero hbuf[0][*][*]
    } else {
        if (t < 64) {
            const float hv = stH[b * 64 + t];
            const short hs = f2bf(hv);
            hbuf[cs & 1][0][t] = (unsigned short)hs;
            hbuf[cs & 1][1][t] = (unsigned short)f2bf(hv - bf2f(hs));
        }
        if (isGate) {
            c = stC[b * 64 + w * 16 + lm];
        } else {
            hkA = stHK[b * 32 + lm];
            if (lm < 10) hkB = stHK[b * 32 + 16 + lm];
        }
    }
    __syncthreads();

    // ---- gx prefetch (distance 2); lane reads cols g*64 + w*16 + lm ----
    const float* gxp = gx + (size_t)b * Tc * G_ + w * 16 + lm;
    float ga0 = 0.f, ga1 = 0.f, ga2 = 0.f, ga3 = 0.f;
    float gb0 = 0.f, gb1 = 0.f, gb2 = 0.f, gb3 = 0.f;
    if (isGate) {
        if (cs < len) { ga0 = gxp[0]; ga1 = gxp[64]; ga2 = gxp[128]; ga3 = gxp[192]; }
        if (cs + 1 < len && cs + 1 < ce) {
            const float* r = gxp + G_;
            gb0 = r[0]; gb1 = r[64]; gb2 = r[128]; gb3 = r[192];
        }
    }

    for (int u = cs; u < ce; ++u) {
        // A-fragments: quad-broadcast reads of h_{u-1} (hi/lo), k = kc*32+quad*8+r.
        const unsigned short* hr = &hbuf[u & 1][0][0];
        const unsigned short* hl = &hbuf[u & 1][1][0];
        const short8 Ah0 = *(const short8*)(hr + quad * 8);
        const short8 Ah1 = *(const short8*)(hr + 32 + quad * 8);
        const short8 Al0 = *(const short8*)(hl + quad * 8);
        const short8 Al1 = *(const short8*)(hl + 32 + quad * 8);

        float vi = 0.f, vf = 0.f, vg = 0.f, vo = 0.f;
        if (isGate) {
            f4 a0 = {0,0,0,0}, a1 = {0,0,0,0}, a2 = {0,0,0,0}, a3 = {0,0,0,0};
            a0 = __builtin_amdgcn_mfma_f32_16x16x32_bf16(Ah0, Bh[0][0], a0, 0, 0, 0);
            a1 = __builtin_amdgcn_mfma_f32_16x16x32_bf16(Ah0, Bh[1][0], a1, 0, 0, 0);
            a2 = __builtin_amdgcn_mfma_f32_16x16x32_bf16(Ah0, Bh[2][0], a2, 0, 0, 0);
            a3 = __builtin_amdgcn_mfma_f32_16x16x32_bf16(Ah0, Bh[3][0], a3, 0, 0, 0);
            a0 = __builtin_amdgcn_mfma_f32_16x16x32_bf16(Al0, Bh[0][0], a0, 0, 0, 0);
            a1 = __builtin_amdgcn_mfma_f32_16x16x32_bf16(Al0, Bh[1][0], a1, 0, 0, 0);
            a2 = __builtin_amdgcn_mfma_f32_16x16x32_bf16(Al0, Bh[2][0], a2, 0, 0, 0);
            a3 = __builtin_amdgcn_mfma_f32_16x16x32_bf16(Al0, Bh[3][0], a3, 0, 0, 0);
            a0 = __builtin_amdgcn_mfma_f32_16x16x32_bf16(Ah0, Bl[0][0], a0, 0, 0, 0);
            a1 = __builtin_amdgcn_mfma_f32_16x16x32_bf16(Ah0, Bl[1][0], a1, 0, 0, 0);
            a2 = __builtin_amdgcn_mfma_f32_16x16x32_bf16(Ah0, Bl[2][0], a2, 0, 0, 0);
            a3 = __builtin_amdgcn_mfma_f32_16x16x32_bf16(Ah0, Bl[3][0], a3, 0, 0, 0);
            a0 = __builtin_amdgcn_mfma_f32_16x16x32_bf16(Ah1, Bh[0][1], a0, 0, 0, 0);
            a1 = __builtin_amdgcn_mfma_f32_16x16x32_bf16(Ah1, Bh[1][1], a1, 0, 0, 0);
            a2 = __builtin_amdgcn_mfma_f32_16x16x32_bf16(Ah1, Bh[2][1], a2, 0, 0, 0);
            a3 = __builtin_amdgcn_mfma_f32_16x16x32_bf16(Ah1, Bh[3][1], a3, 0, 0, 0);
            a0 = __builtin_amdgcn_mfma_f32_16x16x32_bf16(Al1, Bh[0][1], a0, 0, 0, 0);
            a1 = __builtin_amdgcn_mfma_f32_16x16x32_bf16(Al1, Bh[1][1], a1, 0, 0, 0);
            a2 = __builtin_amdgcn_mfma_f32_16x16x32_bf16(Al1, Bh[2][1], a2, 0, 0, 0);
            a3 = __builtin_amdgcn_mfma_f32_16x16x32_bf16(Al1, Bh[3][1], a3, 0, 0, 0);
            a0 = __builtin_amdgcn_mfma_f32_16x16x32_bf16(Ah1, Bl[0][1], a0, 0, 0, 0);
            a1 = __builtin_amdgcn_mfma_f32_16x16x32_bf16(Ah1, Bl[1][1], a1, 0, 0, 0);
            a2 = __builtin_amdgcn_mfma_f32_16x16x32_bf16(Ah1, Bl[2][1], a2, 0, 0, 0);
            a3 = __builtin_amdgcn_mfma_f32_16x16x32_bf16(Ah1, Bl[3][1], a3, 0, 0, 0);
            // all D rows identical (A replicated): element 0 is this lane's col.
            vi = a0[0] + ga0; vf = a1[0] + ga1; vg = a2[0] + ga2; vo = a3[0] + ga3;
        } else if (u >= 1) {
            // head: hk_{u-1} = tanh(hWih·h_{u-1} + hb + hWhh·hk_{u-2})
            f4 z0 = {0,0,0,0}, z1 = {0,0,0,0};
            z0 = __builtin_amdgcn_mfma_f32_16x16x32_bf16(Ah0, KBh[0][0], z0, 0, 0, 0);
            z1 = __builtin_amdgcn_mfma_f32_16x16x32_bf16(Ah0, KBh[1][0], z1, 0, 0, 0);
            z0 = __builtin_amdgcn_mfma_f32_16x16x32_bf16(Al0, KBh[0][0], z0, 0, 0, 0);
            z1 = __builtin_amdgcn_mfma_f32_16x16x32_bf16(Al0, KBh[1][0], z1, 0, 0, 0);
            z0 = __builtin_amdgcn_mfma_f32_16x16x32_bf16(Ah0, KBl[0][0], z0, 0, 0, 0);
            z1 = __builtin_amdgcn_mfma_f32_16x16x32_bf16(Ah0, KBl[1][0], z1, 0, 0, 0);
            z0 = __builtin_amdgcn_mfma_f32_16x16x32_bf16(Ah1, KBh[0][1], z0, 0, 0, 0);
            z1 = __builtin_amdgcn_mfma_f32_16x16x32_bf16(Ah1, KBh[1][1], z1, 0, 0, 0);
            z0 = __builtin_amdgcn_mfma_f32_16x16x32_bf16(Al1, KBh[0][1], z0, 0, 0, 0);
            z1 = __builtin_amdgcn_mfma_f32_16x16x32_bf16(Al1, KBh[1][1], z1, 0, 0, 0);
            z0 = __builtin_amdgcn_mfma_f32_16x16x32_bf16(Ah1, KBl[0][1], z0, 0, 0, 0);
            z1 = __builtin_amdgcn_mfma_f32_16x16x32_bf16(Ah1, KBl[1][1], z1, 0, 0, 0);
            const float zA = z0[0] + hbA;
            const float zB = z1[0] + hbB;
            const float pA = __shfl_xor(hkA, 1);
            const float pB = __shfl_xor(hkB, 1);
            const float a0_ = (lm & 1) ? pA : hkA, a1_ = (lm & 1) ? hkA : pA;
            const float b0_ = (lm & 1) ? pB : hkB, b1_ = (lm & 1) ? hkB : pB;
            hkA = tanh_fast(zA + w0A * a0_ + w1A * a1_);
            hkB = tanh_fast(zB + w0B * b0_ + w1B * b1_);
        }

        if (u == len) {   // uniform per block (1 batch): all waves exit together
            if (!isGate && quad == 0) {
                out[((lm >> 1) * B_ + b) * H2_ + (lm & 1)] = sigm(hkA);
                if (lm < 10) {
                    const int r2 = 16 + lm;
                    out[((r2 >> 1) * B_ + b) * H2_ + (r2 & 1)] = sigm(hkB);
                }
            }
            return;
        }

        if (isGate) {
            c = sigm(vf) * c + sigm(vi) * tanh_fast(vg);
            h = sigm(vo) * tanh_fast(c);
            if (quad == 0) {
                const short hs = f2bf(h);
                hbuf[(u + 1) & 1][0][w * 16 + lm] = (unsigned short)hs;
                hbuf[(u + 1) & 1][1][w * 16 + lm] = (unsigned short)f2bf(h - bf2f(hs));
            }
            ga0 = gb0; ga1 = gb1; ga2 = gb2; ga3 = gb3;
            const int un = u + 2;
            if (un < len && un < ce) {
                const float* r = gxp + (size_t)(un - cs) * G_;
                gb0 = r[0]; gb1 = r[64]; gb2 = r[128]; gb3 = r[192];
            } else {
                gb0 = gb1 = gb2 = gb3 = 0.f;
            }
        }
        sync_lds_only();
    }

    // chunk complete (len >= ce): persist state (exact fp32 from registers)
    if (isGate) {
        if (quad == 0) {
            stH[b * 64 + w * 16 + lm] = h;
            stC[b * 64 + w * 16 + lm] = c;
        }
    } else if (quad == 0) {
        stHK[b * 32 + lm] = hkA;
        if (lm < 10) stHK[b * 32 + 16 + lm] = hkB;
    }

    if (ce == S_ && len == S_ && !isGate) {
        // lagged final head for h_{S-1} (in hbuf[S_&1], written at u=S_-1)
        const unsigned short* hr = &hbuf[S_ & 1][0][0];
        const unsigned short* hl = &hbuf[S_ & 1][1][0];
        const short8 Ah0 = *(const short8*)(hr + quad * 8);
        const short8 Ah1 = *(const short8*)(hr + 32 + quad * 8);
        const short8 Al0 = *(const short8*)(hl + quad * 8);
        const short8 Al1 = *(const short8*)(hl + 32 + quad * 8);
        f4 z0 = {0,0,0,0}, z1 = {0,0,0,0};
        z0 = __builtin_amdgcn_mfma_f32_16x16x32_bf16(Ah0, KBh[0][0], z0, 0, 0, 0);
        z1 = __builtin_amdgcn_mfma_f32_16x16x32_bf16(Ah0, KBh[1][0], z1, 0, 0, 0);
        z0 = __builtin_amdgcn_mfma_f32_16x16x32_bf16(Al0, KBh[0][0], z0, 0, 0, 0);
        z1 = __builtin_amdgcn_mfma_f32_16x16x32_bf16(Al0, KBh[1][0], z1, 0, 0, 0);
        z0 = __builtin_amdgcn_mfma_f32_16x16x32_bf16(Ah0, KBl[0][0], z0, 0, 0, 0);
        z1 = __builtin_amdgcn_mfma_f32_16x16x32_bf16(Ah0, KBl[1][0], z1, 0, 0, 0);
        z0 = __builtin_amdgcn_mfma_f32_16x16x32_bf16(Ah1, KBh[0][1], z0, 0, 0, 0);
        z1 = __builtin_amdgcn_mfma_f32_16x16x32_bf16(Ah1, KBh[1][1], z1, 0, 0, 0);
        z0 = __builtin_amdgcn_mfma_f32_16x16x32_bf16(Al1, KBh[0][1], z0, 0, 0, 0);
        z1 = __builtin_amdgcn_mfma_f32_16x16x32_bf16(Al1, KBh[1][1], z1, 0, 0, 0);
        z0 = __builtin_amdgcn_mfma_f32_16x16x32_bf16(Ah1, KBl[0][1], z0, 0, 0, 0);
        z1 = __builtin_amdgcn_mfma_f32_16x16x32_bf16(Ah1, KBl[1][1], z1, 0, 0, 0);
        const float zA = z0[0] + hbA;
        const float zB = z1[0] + hbB;
        const float pA = __shfl_xor(hkA, 1);
        const float pB = __shfl_xor(hkB, 1);
        const float a0_ = (lm & 1) ? pA : hkA, a1_ = (lm & 1) ? hkA : pA;
        const float b0_ = (lm & 1) ? pB : hkB, b1_ = (lm & 1) ? hkB : pB;
        const float fA = tanh_fast(zA + w0A * a0_ + w1A * a1_);
        const float fB = tanh_fast(zB + w0B * b0_ + w1B * b1_);
        if (quad == 0) {
            out[((lm >> 1) * B_ + b) * H2_ + (lm & 1)] = sigm(fA);
            if (lm < 10) {
                const int r2 = 16 + lm;
                out[((r2 >> 1) * B_ + b) * H2_ + (r2 & 1)] = sigm(fB);
            }
        }
    }
}

}  // namespace

extern "C" void kernel_launch(void* const* d_in, const int* in_sizes, int n_in,
                              void* d_out, int out_size, void* d_ws, size_t ws_size,
                              hipStream_t stream) {
    const float* x    = (const float*)d_in[0];
    const int*   len  = (const int*)d_in[1];
    const float* Wih  = (const float*)d_in[2];
    const float* Whh  = (const float*)d_in[3];
    const float* bih  = (const float*)d_in[4];
    const float* bhh  = (const float*)d_in[5];
    const float* hWih = (const float*)d_in[6];
    const float* hWhh = (const float*)d_in[7];
    const float* hbih = (const float*)d_in[8];
    const float* hbhh = (const float*)d_in[9];
    float* out = (float*)d_out;

    // pick chunk length fitting the workspace (gx chunk + 160KB state)
    int tcLog = 8;  // Tc = 256
    while (tcLog > 5) {
        size_t need = (size_t)B_ * ((size_t)1 << tcLog) * G_ * 4 + 160 * 1024;
        if (need <= ws_size) break;
        --tcLog;
    }
    const int Tc = 1 << tcLog;
    float* gxbuf = (float*)d_ws;
    size_t gxBytes = (size_t)B_ * Tc * G_ * 4;
    float* stH  = (float*)((char*)d_ws + gxBytes);
    float* stC  = stH + B_ * 64;
    float* stHK = stC + B_ * 64;   // B*32 floats used

    for (int cs = 0; cs < S_; cs += Tc) {
        dim3 g1(B_ * Tc / 128, 2);
        hipLaunchKernelGGL(k1_gemm, g1, dim3(256), 0, stream,
                           x, len, Wih, bih, bhh, gxbuf, cs, tcLog);
        hipLaunchKernelGGL(k2_recur, dim3(B_), dim3(320), 0, stream,
                           gxbuf, len, Whh, hWih, hWhh, hbih, hbhh, out,
                           stH, stC, stHK, cs, Tc);
    }
}